// Round 3
// baseline (823.047 us; speedup 1.0000x reference)
//
#include <hip/hip_runtime.h>
#include <hip/hip_bf16.h>

// N=8192, D=512.  Q = emb@Wqk^T+bqk (K==Q); out = softmax(QK^T/sqrt(512)) @ V.
// Softmax rows sum to 1 => out = (softmax(S) @ emb) @ Wv^T + bv, so V is never
// materialized. Device dtype of in/out is UNKNOWN (fp32 reference, but harness
// may store bf16) -- a probe kernel detects it at runtime (flag in d_ws) and
// all kernels branch uniformly. Internal pipeline: bf16 MFMA, fp32 accum.
// Scores bounded (~9.4 max) => softmax without max-subtraction.
// ws usage: 16 B flag + 8 MB Q(bf16). Final V-proj fused into attn kernel
// (T tile through LDS) so no other scratch exists.

#define NTOK 8192
#define DIM  512

typedef unsigned short ushort_t;
typedef __attribute__((ext_vector_type(8))) __bf16 bf16x8;
typedef __attribute__((ext_vector_type(4))) float f32x4;

__device__ __forceinline__ float bf2f(ushort_t u) {
    union { unsigned int i; float f; } v; v.i = ((unsigned int)u) << 16; return v.f;
}
__device__ __forceinline__ ushort_t f2bf(float f) {
    union { float f; unsigned int i; } v; v.f = f;
    unsigned int b = v.i;
    return (ushort_t)((b + 0x7FFFu + ((b >> 16) & 1u)) >> 16);   // RNE
}
__device__ __forceinline__ __bf16 f2bfh(float f) {
    union { ushort_t u; __bf16 h; } c; c.u = f2bf(f); return c.h;
}
__device__ __forceinline__ f32x4 mfma16(bf16x8 a, bf16x8 b, f32x4 c) {
    return __builtin_amdgcn_mfma_f32_16x16x32_bf16(a, b, c, 0, 0, 0);
}
// 8-element MFMA fragment load from either dtype (idx multiple of 8)
__device__ __forceinline__ bf16x8 load8(const void* p, size_t idx, bool f32) {
    if (f32) {
        const float* f = (const float*)p + idx;
        bf16x8 r;
        #pragma unroll
        for (int j = 0; j < 8; ++j) r[j] = f2bfh(f[j]);
        return r;
    }
    return *(const bf16x8*)((const ushort_t*)p + idx);
}
__device__ __forceinline__ float loadS(const void* p, size_t idx, bool f32) {
    return f32 ? ((const float*)p)[idx] : bf2f(((const ushort_t*)p)[idx]);
}

#define LDA 520   // 512+8 pad
#define LDP 136   // 128+8 pad

// ---------------------------------------------------------------------------
// Dtype probe: even-indexed ushorts of genuine-bf16 N(0,1) data are ~100%
// "sane" (exponent near bias, or zero); fp32 data read as bf16 gives random
// exponents in even slots (~13% sane). flag=1 => bf16.
// ---------------------------------------------------------------------------
__global__ void detect_kernel(const ushort_t* __restrict__ emb, int* __restrict__ flag)
{
    int lane = threadIdx.x;   // 64 threads, 1 block
    int cnt = 0;
    #pragma unroll
    for (int i = 0; i < 8; ++i) {
        ushort_t u = emb[(size_t)(lane * 8 + i) * 2];   // even indices 0..1022
        int a = u & 0x7FFF;
        int e = (u >> 7) & 0xFF;
        if (a == 0 || (e >= 111 && e <= 143)) cnt++;    // zero or |x| in [2^-16,2^16]
    }
    cnt += __shfl_xor(cnt, 1);  cnt += __shfl_xor(cnt, 2);  cnt += __shfl_xor(cnt, 4);
    cnt += __shfl_xor(cnt, 8);  cnt += __shfl_xor(cnt, 16); cnt += __shfl_xor(cnt, 32);
    if (lane == 0) *flag = (cnt >= 460) ? 1 : 0;
}

// ---------------------------------------------------------------------------
// Q[8192][512](bf16, in ws) = emb @ Wqk^T + bqk.  256 blocks x 512 thr.
// ---------------------------------------------------------------------------
__global__ __launch_bounds__(512)
void projq_kernel(const int* __restrict__ flag, const void* __restrict__ emb,
                  const void* __restrict__ W, const void* __restrict__ bias,
                  ushort_t* __restrict__ C)
{
    __shared__ ushort_t Alds[32][LDA];
    const bool f32 = (*flag == 0);

    const int tid  = threadIdx.x;
    const int wave = tid >> 6;
    const int lane = tid & 63;
    const int quad = lane >> 4;
    const int col  = lane & 15;
    const int mblk = blockIdx.x * 32;

    #pragma unroll
    for (int i = 0; i < 4; ++i) {
        int chunk = i * 512 + tid;
        int row = chunk >> 6;
        int k8  = (chunk & 63) * 8;
        *(bf16x8*)&Alds[row][k8] = load8(emb, (size_t)(mblk + row) * 512 + k8, f32);
    }
    __syncthreads();

    f32x4 acc[2][4];
    #pragma unroll
    for (int r = 0; r < 2; ++r)
        #pragma unroll
        for (int c = 0; c < 4; ++c) acc[r][c] = (f32x4){0.f, 0.f, 0.f, 0.f};

    const int wcol = wave * 64;
    #pragma unroll
    for (int kk = 0; kk < 16; ++kk) {
        bf16x8 a0 = *(const bf16x8*)&Alds[col][kk * 32 + quad * 8];
        bf16x8 a1 = *(const bf16x8*)&Alds[16 + col][kk * 32 + quad * 8];
        #pragma unroll
        for (int c = 0; c < 4; ++c) {
            bf16x8 b = load8(W, (size_t)(wcol + c * 16 + col) * 512 + kk * 32 + quad * 8, f32);
            acc[0][c] = mfma16(a0, b, acc[0][c]);
            acc[1][c] = mfma16(a1, b, acc[1][c]);
        }
    }

    #pragma unroll
    for (int r = 0; r < 2; ++r)
        #pragma unroll
        for (int c = 0; c < 4; ++c)
            #pragma unroll
            for (int g = 0; g < 4; ++g) {
                int m = mblk + r * 16 + quad * 4 + g;
                int n = wcol + c * 16 + col;
                C[(size_t)m * DIM + n] = f2bf(acc[r][c][g] + loadS(bias, n, f32));
            }
}

// ---------------------------------------------------------------------------
// Fused: T = softmax(QQ^T/sqrt(512)) @ emb (through LDS), out = T @ Wv^T + bv.
// 256 blocks x 512 thr; 32 Q-rows/block; key tile 128/iter.
// Wave w: S cols [16w,16w+16); T/out cols [64w,64w+64).
// ---------------------------------------------------------------------------
__global__ __launch_bounds__(512)
void attn_kernel(const int* __restrict__ flag, const ushort_t* __restrict__ Q,
                 const void* __restrict__ emb, const void* __restrict__ Wv,
                 const void* __restrict__ bv, void* __restrict__ Out)
{
    __shared__ ushort_t Qlds[32][LDA];   // Q tile; reused for T tile after main loop
    __shared__ ushort_t Plds[32][LDP];
    __shared__ float    Lpart[8][32];

    const bool f32 = (*flag == 0);
    const int tid  = threadIdx.x;
    const int wave = tid >> 6;
    const int lane = tid & 63;
    const int quad = lane >> 4;
    const int col  = lane & 15;
    const int q0   = blockIdx.x * 32;

    #pragma unroll
    for (int i = 0; i < 4; ++i) {
        int chunk = i * 512 + tid;
        int row = chunk >> 6;
        int k8  = (chunk & 63) * 8;
        *(bf16x8*)&Qlds[row][k8] = *(const bf16x8*)&Q[(size_t)(q0 + row) * 512 + k8];
    }
    __syncthreads();

    f32x4 accO[2][4];
    #pragma unroll
    for (int r = 0; r < 2; ++r)
        #pragma unroll
        for (int c = 0; c < 4; ++c) accO[r][c] = (f32x4){0.f, 0.f, 0.f, 0.f};

    float lsum[2][4];
    #pragma unroll
    for (int r = 0; r < 2; ++r)
        #pragma unroll
        for (int g = 0; g < 4; ++g) lsum[r][g] = 0.f;

    const float sc = 0.04419417382415922f * 1.4426950408889634f;  // 1/sqrt(512)*log2e
    const int wOcol = wave * 64;

    for (int j0 = 0; j0 < NTOK; j0 += 128) {
        // ---- S = Q_tile @ K_tile^T (this wave's 16 keys; K rows = Q rows) ----
        f32x4 accS[2];
        accS[0] = (f32x4){0.f, 0.f, 0.f, 0.f};
        accS[1] = (f32x4){0.f, 0.f, 0.f, 0.f};
        const size_t keyrow = (size_t)(j0 + wave * 16 + col) * 512;
        #pragma unroll
        for (int kk = 0; kk < 16; ++kk) {
            bf16x8 b  = *(const bf16x8*)&Q[keyrow + kk * 32 + quad * 8];
            bf16x8 a0 = *(const bf16x8*)&Qlds[col][kk * 32 + quad * 8];
            bf16x8 a1 = *(const bf16x8*)&Qlds[16 + col][kk * 32 + quad * 8];
            accS[0] = mfma16(a0, b, accS[0]);
            accS[1] = mfma16(a1, b, accS[1]);
        }

        __syncthreads();   // previous PV phase done reading Plds

        #pragma unroll
        for (int r = 0; r < 2; ++r)
            #pragma unroll
            for (int g = 0; g < 4; ++g) {
                float p = exp2f(fminf(accS[r][g] * sc, 126.0f));
                lsum[r][g] += p;
                Plds[r * 16 + quad * 4 + g][wave * 16 + col] = f2bf(p);
            }

        __syncthreads();   // P visible to all waves

        // ---- T += P @ emb_tile (this wave's 64 dims) ----
        #pragma unroll
        for (int kk = 0; kk < 4; ++kk) {
            bf16x8 a0 = *(const bf16x8*)&Plds[col][kk * 32 + quad * 8];
            bf16x8 a1 = *(const bf16x8*)&Plds[16 + col][kk * 32 + quad * 8];
            #pragma unroll
            for (int c = 0; c < 4; ++c) {
                bf16x8 b;
                size_t base = (size_t)(j0 + kk * 32 + quad * 8) * 512 + (wOcol + c * 16 + col);
                if (f32) {
                    const float* bp = (const float*)emb + base;
                    #pragma unroll
                    for (int j = 0; j < 8; ++j) b[j] = f2bfh(bp[(size_t)j * 512]);
                } else {
                    const __bf16* bp = (const __bf16*)emb + base;
                    #pragma unroll
                    for (int j = 0; j < 8; ++j) b[j] = bp[(size_t)j * 512];
                }
                accO[0][c] = mfma16(a0, b, accO[0][c]);
                accO[1][c] = mfma16(a1, b, accO[1][c]);
            }
        }
    }

    // ---- softmax denominators ----
    #pragma unroll
    for (int r = 0; r < 2; ++r)
        #pragma unroll
        for (int g = 0; g < 4; ++g) {
            float s = lsum[r][g];
            s += __shfl_xor(s, 1);
            s += __shfl_xor(s, 2);
            s += __shfl_xor(s, 4);
            s += __shfl_xor(s, 8);
            lsum[r][g] = s;
        }
    if (col == 0) {
        #pragma unroll
        for (int r = 0; r < 2; ++r)
            #pragma unroll
            for (int g = 0; g < 4; ++g)
                Lpart[wave][r * 16 + quad * 4 + g] = lsum[r][g];
    }
    __syncthreads();   // Lpart ready; also: all waves done with main loop (Qlds free)

    // ---- normalize, write T tile into Qlds (reuse) ----
    #pragma unroll
    for (int r = 0; r < 2; ++r) {
        float rinv[4];
        #pragma unroll
        for (int g = 0; g < 4; ++g) {
            float t = 0.f;
            #pragma unroll
            for (int w = 0; w < 8; ++w) t += Lpart[w][r * 16 + quad * 4 + g];
            rinv[g] = 1.0f / t;
        }
        #pragma unroll
        for (int c = 0; c < 4; ++c)
            #pragma unroll
            for (int g = 0; g < 4; ++g)
                Qlds[r * 16 + quad * 4 + g][wOcol + c * 16 + col] = f2bf(accO[r][c][g] * rinv[g]);
    }
    __syncthreads();

    // ---- out = T @ Wv^T + bv ----
    f32x4 acc2[2][4];
    #pragma unroll
    for (int r = 0; r < 2; ++r)
        #pragma unroll
        for (int c = 0; c < 4; ++c) acc2[r][c] = (f32x4){0.f, 0.f, 0.f, 0.f};

    #pragma unroll
    for (int kk = 0; kk < 16; ++kk) {
        bf16x8 a0 = *(const bf16x8*)&Qlds[col][kk * 32 + quad * 8];
        bf16x8 a1 = *(const bf16x8*)&Qlds[16 + col][kk * 32 + quad * 8];
        #pragma unroll
        for (int c = 0; c < 4; ++c) {
            bf16x8 b = load8(Wv, (size_t)(wOcol + c * 16 + col) * 512 + kk * 32 + quad * 8, f32);
            acc2[0][c] = mfma16(a0, b, acc2[0][c]);
            acc2[1][c] = mfma16(a1, b, acc2[1][c]);
        }
    }

    #pragma unroll
    for (int r = 0; r < 2; ++r)
        #pragma unroll
        for (int c = 0; c < 4; ++c)
            #pragma unroll
            for (int g = 0; g < 4; ++g) {
                int m = q0 + r * 16 + quad * 4 + g;
                int n = wOcol + c * 16 + col;
                float v = acc2[r][c][g] + loadS(bv, n, f32);
                if (f32) ((float*)Out)[(size_t)m * DIM + n] = v;
                else     ((ushort_t*)Out)[(size_t)m * DIM + n] = f2bf(v);
            }
}

extern "C" void kernel_launch(void* const* d_in, const int* in_sizes, int n_in,
                              void* d_out, int out_size, void* d_ws, size_t ws_size,
                              hipStream_t stream)
{
    const void* emb = d_in[0];
    const void* Wqk = d_in[1];
    const void* bqk = d_in[2];
    const void* Wv  = d_in[3];
    const void* bv  = d_in[4];

    int*      flag = (int*)d_ws;
    ushort_t* Qws  = (ushort_t*)d_ws + 8;   // byte offset 16; 8 MB bf16 Q

    detect_kernel<<<dim3(1), dim3(64), 0, stream>>>((const ushort_t*)emb, flag);
    projq_kernel<<<dim3(NTOK / 32), dim3(512), 0, stream>>>(flag, emb, Wqk, bqk, Qws);
    attn_kernel<<<dim3(NTOK / 32), dim3(512), 0, stream>>>(flag, Qws, emb, Wv, bv, d_out);
}

// Round 4
// 636.785 us; speedup vs baseline: 1.2925x; 1.2925x over previous
//
#include <hip/hip_runtime.h>
#include <hip/hip_bf16.h>

// N=8192, D=512.  Q = emb@Wqk^T+bqk (K==Q); out = softmax(QK^T/sqrt(512)) @ V.
// Softmax rows sum to 1 => out = (softmax(S) @ emb) @ Wv^T + bv (V never built).
// Device dtype detected at runtime (flag in d_ws); round-3 evidence: fp32.
// Internal pipeline: bf16 MFMA, fp32 accum.
// Fast path (ws >= 16MB+64): embT bf16 [512][8192] staged in ws so PV
// B-fragments are contiguous 16B/lane (round-3 profile: scalar stride-2048B
// gathers made attn latency-bound, MfmaUtil 7.8%). Fallback: gather version.

#define NTOK 8192
#define DIM  512

typedef unsigned short ushort_t;
typedef __attribute__((ext_vector_type(8))) __bf16 bf16x8;
typedef __attribute__((ext_vector_type(4))) float f32x4;

__device__ __forceinline__ float bf2f(ushort_t u) {
    union { unsigned int i; float f; } v; v.i = ((unsigned int)u) << 16; return v.f;
}
__device__ __forceinline__ ushort_t f2bf(float f) {
    union { float f; unsigned int i; } v; v.f = f;
    unsigned int b = v.i;
    return (ushort_t)((b + 0x7FFFu + ((b >> 16) & 1u)) >> 16);   // RNE
}
__device__ __forceinline__ __bf16 f2bfh(float f) {
    union { ushort_t u; __bf16 h; } c; c.u = f2bf(f); return c.h;
}
__device__ __forceinline__ f32x4 mfma16(bf16x8 a, bf16x8 b, f32x4 c) {
    return __builtin_amdgcn_mfma_f32_16x16x32_bf16(a, b, c, 0, 0, 0);
}
__device__ __forceinline__ bf16x8 load8(const void* p, size_t idx, bool f32) {
    if (f32) {
        const float* f = (const float*)p + idx;
        bf16x8 r;
        #pragma unroll
        for (int j = 0; j < 8; ++j) r[j] = f2bfh(f[j]);
        return r;
    }
    return *(const bf16x8*)((const ushort_t*)p + idx);
}
__device__ __forceinline__ float loadS(const void* p, size_t idx, bool f32) {
    return f32 ? ((const float*)p)[idx] : bf2f(((const ushort_t*)p)[idx]);
}

#define LDA 520   // 512+8 pad
#define LDP 136   // 128+8 pad

// ---------------------------------------------------------------------------
// Dtype probe: flag=1 => bf16 data, flag=0 => fp32.
// ---------------------------------------------------------------------------
__global__ void detect_kernel(const ushort_t* __restrict__ emb, int* __restrict__ flag)
{
    int lane = threadIdx.x;   // 64 threads, 1 block
    int cnt = 0;
    #pragma unroll
    for (int i = 0; i < 8; ++i) {
        ushort_t u = emb[(size_t)(lane * 8 + i) * 2];
        int a = u & 0x7FFF;
        int e = (u >> 7) & 0xFF;
        if (a == 0 || (e >= 111 && e <= 143)) cnt++;
    }
    cnt += __shfl_xor(cnt, 1);  cnt += __shfl_xor(cnt, 2);  cnt += __shfl_xor(cnt, 4);
    cnt += __shfl_xor(cnt, 8);  cnt += __shfl_xor(cnt, 16); cnt += __shfl_xor(cnt, 32);
    if (lane == 0) *flag = (cnt >= 460) ? 1 : 0;
}

// ---------------------------------------------------------------------------
// embT[512][8192] (bf16) = emb^T.  Tile 64 tokens x 64 dims, 256 thr/block.
// ---------------------------------------------------------------------------
__global__ __launch_bounds__(256)
void transpose_kernel(const int* __restrict__ flag, const void* __restrict__ emb,
                      ushort_t* __restrict__ embT)
{
    __shared__ float tile[64][65];
    const bool f32 = (*flag == 0);
    const int t  = threadIdx.x;
    const int j0 = blockIdx.x * 64;
    const int d0 = blockIdx.y * 64;

    {   // load 64x64: 4 threads per token row, 16 floats each
        int r = t >> 2, cs = (t & 3) * 16;
        if (f32) {
            const float* src = (const float*)emb + (size_t)(j0 + r) * DIM + d0 + cs;
            #pragma unroll
            for (int i = 0; i < 16; i += 4) {
                float4 v = *(const float4*)(src + i);
                tile[r][cs + i]     = v.x;
                tile[r][cs + i + 1] = v.y;
                tile[r][cs + i + 2] = v.z;
                tile[r][cs + i + 3] = v.w;
            }
        } else {
            const ushort_t* src = (const ushort_t*)emb + (size_t)(j0 + r) * DIM + d0 + cs;
            #pragma unroll
            for (int i = 0; i < 16; ++i) tile[r][cs + i] = bf2f(src[i]);
        }
    }
    __syncthreads();
    {   // store transposed: 4 threads per dim row, 16 bf16 each (32 B)
        int d = t >> 2, js = (t & 3) * 16;
        ushort_t buf[16];
        #pragma unroll
        for (int i = 0; i < 16; ++i) buf[i] = f2bf(tile[js + i][d]);
        ushort_t* dst = embT + (size_t)(d0 + d) * NTOK + j0 + js;
        *(uint4*)dst       = *(uint4*)&buf[0];
        *(uint4*)(dst + 8) = *(uint4*)&buf[8];
    }
}

// ---------------------------------------------------------------------------
// Q[8192][512](bf16, ws) = emb @ Wqk^T + bqk.  256 blocks x 512 thr.
// ---------------------------------------------------------------------------
__global__ __launch_bounds__(512)
void projq_kernel(const int* __restrict__ flag, const void* __restrict__ emb,
                  const void* __restrict__ W, const void* __restrict__ bias,
                  ushort_t* __restrict__ C)
{
    __shared__ ushort_t Alds[32][LDA];
    const bool f32 = (*flag == 0);

    const int tid  = threadIdx.x;
    const int wave = tid >> 6;
    const int lane = tid & 63;
    const int quad = lane >> 4;
    const int col  = lane & 15;
    const int mblk = blockIdx.x * 32;

    #pragma unroll
    for (int i = 0; i < 4; ++i) {
        int chunk = i * 512 + tid;
        int row = chunk >> 6;
        int k8  = (chunk & 63) * 8;
        *(bf16x8*)&Alds[row][k8] = load8(emb, (size_t)(mblk + row) * 512 + k8, f32);
    }
    __syncthreads();

    f32x4 acc[2][4];
    #pragma unroll
    for (int r = 0; r < 2; ++r)
        #pragma unroll
        for (int c = 0; c < 4; ++c) acc[r][c] = (f32x4){0.f, 0.f, 0.f, 0.f};

    const int wcol = wave * 64;
    #pragma unroll
    for (int kk = 0; kk < 16; ++kk) {
        bf16x8 a0 = *(const bf16x8*)&Alds[col][kk * 32 + quad * 8];
        bf16x8 a1 = *(const bf16x8*)&Alds[16 + col][kk * 32 + quad * 8];
        #pragma unroll
        for (int c = 0; c < 4; ++c) {
            bf16x8 b = load8(W, (size_t)(wcol + c * 16 + col) * 512 + kk * 32 + quad * 8, f32);
            acc[0][c] = mfma16(a0, b, acc[0][c]);
            acc[1][c] = mfma16(a1, b, acc[1][c]);
        }
    }

    #pragma unroll
    for (int r = 0; r < 2; ++r)
        #pragma unroll
        for (int c = 0; c < 4; ++c)
            #pragma unroll
            for (int g = 0; g < 4; ++g) {
                int m = mblk + r * 16 + quad * 4 + g;
                int n = wcol + c * 16 + col;
                C[(size_t)m * DIM + n] = f2bf(acc[r][c][g] + loadS(bias, n, f32));
            }
}

// ---------------------------------------------------------------------------
// Fused attention + V-projection. Template VT=1: V-operand from embT (bf16
// [512][8192], contiguous 16B/lane). VT=0: gather from row-major emb (fallback).
// 256 blocks x 512 thr; 32 Q-rows/block; key tile 128/iter.
// ---------------------------------------------------------------------------
template <int VT>
__global__ __launch_bounds__(512)
void attn_kernel(const int* __restrict__ flag, const ushort_t* __restrict__ Q,
                 const void* __restrict__ embOrT, const void* __restrict__ Wv,
                 const void* __restrict__ bv, void* __restrict__ Out)
{
    __shared__ ushort_t Qlds[32][LDA];   // Q tile; reused as T tile after main loop
    __shared__ ushort_t Plds[32][LDP];
    __shared__ float    Lpart[8][32];

    const bool f32 = (*flag == 0);
    const int tid  = threadIdx.x;
    const int wave = tid >> 6;
    const int lane = tid & 63;
    const int quad = lane >> 4;
    const int col  = lane & 15;
    const int q0   = blockIdx.x * 32;

    #pragma unroll
    for (int i = 0; i < 4; ++i) {
        int chunk = i * 512 + tid;
        int row = chunk >> 6;
        int k8  = (chunk & 63) * 8;
        *(bf16x8*)&Qlds[row][k8] = *(const bf16x8*)&Q[(size_t)(q0 + row) * 512 + k8];
    }
    __syncthreads();

    f32x4 accO[2][4];
    #pragma unroll
    for (int r = 0; r < 2; ++r)
        #pragma unroll
        for (int c = 0; c < 4; ++c) accO[r][c] = (f32x4){0.f, 0.f, 0.f, 0.f};

    float lsum[2][4];
    #pragma unroll
    for (int r = 0; r < 2; ++r)
        #pragma unroll
        for (int g = 0; g < 4; ++g) lsum[r][g] = 0.f;

    const float sc = 0.04419417382415922f * 1.4426950408889634f;  // 1/sqrt(512)*log2e
    const int wOcol = wave * 64;

    for (int j0 = 0; j0 < NTOK; j0 += 128) {
        // ---- S = Q_tile @ K_tile^T (this wave's 16 keys; K == Q) ----
        f32x4 accS[2];
        accS[0] = (f32x4){0.f, 0.f, 0.f, 0.f};
        accS[1] = (f32x4){0.f, 0.f, 0.f, 0.f};
        const size_t keyrow = (size_t)(j0 + wave * 16 + col) * 512;
        #pragma unroll
        for (int kk = 0; kk < 16; ++kk) {
            bf16x8 b  = *(const bf16x8*)&Q[keyrow + kk * 32 + quad * 8];
            bf16x8 a0 = *(const bf16x8*)&Qlds[col][kk * 32 + quad * 8];
            bf16x8 a1 = *(const bf16x8*)&Qlds[16 + col][kk * 32 + quad * 8];
            accS[0] = mfma16(a0, b, accS[0]);
            accS[1] = mfma16(a1, b, accS[1]);
        }

        __syncthreads();   // previous PV phase done reading Plds

        #pragma unroll
        for (int r = 0; r < 2; ++r)
            #pragma unroll
            for (int g = 0; g < 4; ++g) {
                float p = exp2f(fminf(accS[r][g] * sc, 126.0f));
                lsum[r][g] += p;
                Plds[r * 16 + quad * 4 + g][wave * 16 + col] = f2bf(p);
            }

        __syncthreads();   // P visible to all waves

        // ---- T += P @ emb_tile (this wave's 64 dims) ----
        #pragma unroll
        for (int kk = 0; kk < 4; ++kk) {
            bf16x8 a0 = *(const bf16x8*)&Plds[col][kk * 32 + quad * 8];
            bf16x8 a1 = *(const bf16x8*)&Plds[16 + col][kk * 32 + quad * 8];
            #pragma unroll
            for (int c = 0; c < 4; ++c) {
                bf16x8 b;
                if (VT) {
                    b = *(const bf16x8*)((const ushort_t*)embOrT
                        + (size_t)(wOcol + c * 16 + col) * NTOK + j0 + kk * 32 + quad * 8);
                } else {
                    size_t base = (size_t)(j0 + kk * 32 + quad * 8) * 512 + (wOcol + c * 16 + col);
                    if (f32) {
                        const float* bp = (const float*)embOrT + base;
                        #pragma unroll
                        for (int j = 0; j < 8; ++j) b[j] = f2bfh(bp[(size_t)j * 512]);
                    } else {
                        const __bf16* bp = (const __bf16*)embOrT + base;
                        #pragma unroll
                        for (int j = 0; j < 8; ++j) b[j] = bp[(size_t)j * 512];
                    }
                }
                accO[0][c] = mfma16(a0, b, accO[0][c]);
                accO[1][c] = mfma16(a1, b, accO[1][c]);
            }
        }
    }

    // ---- softmax denominators ----
    #pragma unroll
    for (int r = 0; r < 2; ++r)
        #pragma unroll
        for (int g = 0; g < 4; ++g) {
            float s = lsum[r][g];
            s += __shfl_xor(s, 1);
            s += __shfl_xor(s, 2);
            s += __shfl_xor(s, 4);
            s += __shfl_xor(s, 8);
            lsum[r][g] = s;
        }
    if (col == 0) {
        #pragma unroll
        for (int r = 0; r < 2; ++r)
            #pragma unroll
            for (int g = 0; g < 4; ++g)
                Lpart[wave][r * 16 + quad * 4 + g] = lsum[r][g];
    }
    __syncthreads();   // Lpart ready; all waves past main loop (Qlds reusable)

    // ---- normalize, write T tile into Qlds ----
    #pragma unroll
    for (int r = 0; r < 2; ++r) {
        float rinv[4];
        #pragma unroll
        for (int g = 0; g < 4; ++g) {
            float t = 0.f;
            #pragma unroll
            for (int w = 0; w < 8; ++w) t += Lpart[w][r * 16 + quad * 4 + g];
            rinv[g] = 1.0f / t;
        }
        #pragma unroll
        for (int c = 0; c < 4; ++c)
            #pragma unroll
            for (int g = 0; g < 4; ++g)
                Qlds[r * 16 + quad * 4 + g][wOcol + c * 16 + col] = f2bf(accO[r][c][g] * rinv[g]);
    }
    __syncthreads();

    // ---- out = T @ Wv^T + bv ----
    f32x4 acc2[2][4];
    #pragma unroll
    for (int r = 0; r < 2; ++r)
        #pragma unroll
        for (int c = 0; c < 4; ++c) acc2[r][c] = (f32x4){0.f, 0.f, 0.f, 0.f};

    #pragma unroll
    for (int kk = 0; kk < 16; ++kk) {
        bf16x8 a0 = *(const bf16x8*)&Qlds[col][kk * 32 + quad * 8];
        bf16x8 a1 = *(const bf16x8*)&Qlds[16 + col][kk * 32 + quad * 8];
        #pragma unroll
        for (int c = 0; c < 4; ++c) {
            bf16x8 b = load8(Wv, (size_t)(wOcol + c * 16 + col) * 512 + kk * 32 + quad * 8, f32);
            acc2[0][c] = mfma16(a0, b, acc2[0][c]);
            acc2[1][c] = mfma16(a1, b, acc2[1][c]);
        }
    }

    #pragma unroll
    for (int r = 0; r < 2; ++r)
        #pragma unroll
        for (int c = 0; c < 4; ++c)
            #pragma unroll
            for (int g = 0; g < 4; ++g) {
                int m = q0 + r * 16 + quad * 4 + g;
                int n = wOcol + c * 16 + col;
                float v = acc2[r][c][g] + loadS(bv, n, f32);
                if (f32) ((float*)Out)[(size_t)m * DIM + n] = v;
                else     ((ushort_t*)Out)[(size_t)m * DIM + n] = f2bf(v);
            }
}

extern "C" void kernel_launch(void* const* d_in, const int* in_sizes, int n_in,
                              void* d_out, int out_size, void* d_ws, size_t ws_size,
                              hipStream_t stream)
{
    const void* emb = d_in[0];
    const void* Wqk = d_in[1];
    const void* bqk = d_in[2];
    const void* Wv  = d_in[3];
    const void* bv  = d_in[4];

    int*      flag = (int*)d_ws;
    ushort_t* embT = (ushort_t*)d_ws + 32;                       // offset 64 B
    ushort_t* Qws  = embT + (size_t)DIM * NTOK;                  // +8 MB

    const size_t need = 64 + 2 * (size_t)DIM * NTOK * 2;         // 16 MB + 64
    const bool fast = (ws_size >= need);

    detect_kernel<<<dim3(1), dim3(64), 0, stream>>>((const ushort_t*)emb, flag);
    if (fast) {
        transpose_kernel<<<dim3(NTOK / 64, DIM / 64), dim3(256), 0, stream>>>(flag, emb, embT);
        projq_kernel<<<dim3(NTOK / 32), dim3(512), 0, stream>>>(flag, emb, Wqk, bqk, Qws);
        attn_kernel<1><<<dim3(NTOK / 32), dim3(512), 0, stream>>>(flag, Qws, embT, Wv, bv, d_out);
    } else {
        ushort_t* Qsm = (ushort_t*)d_ws + 32;   // only 8 MB used
        projq_kernel<<<dim3(NTOK / 32), dim3(512), 0, stream>>>(flag, emb, Wqk, bqk, Qsm);
        attn_kernel<0><<<dim3(NTOK / 32), dim3(512), 0, stream>>>(flag, Qsm, emb, Wv, bv, d_out);
    }
}